// Round 7
// baseline (389.595 us; speedup 1.0000x reference)
//
#include <hip/hip_runtime.h>
#include <hip/hip_bf16.h>
#include <math.h>

#define LP 1000
#define NCMP 64
#define NSPLIT 5

__device__ __forceinline__ float rcp_fast(float x) { return __builtin_amdgcn_rcpf(x); }

// ---------------- GEMM body: Y[M,128] = op(X)[M,K] @ W[K,128] + b ----------------
// 32-row tile, 256 threads, thread = 4x4, X transposed in LDS, software-pipelined.
// MERGE: X is the NSPLIT-way KV-split flash partial stack, m/l merge applied on load.
template<bool RELU_IN, bool MERGE>
__device__ __forceinline__ void gemm_body(const float* X,
                                          const float* __restrict__ mp, const float* __restrict__ lp,
                                          const float* W, const float* __restrict__ bias,
                                          float* Y, int K, int rowbase)
{
    __shared__ __align__(16) float Ws[32][128];
    __shared__ __align__(16) float Xt[32][36];
    const int t  = threadIdx.x;
    const int r0 = (t >> 5) * 4;
    const int c0 = (t & 31) * 4;
    const int xr = t >> 3, xk = (t & 7) << 2;
    const int xrow = rowbase + xr;
    float wgt[NSPLIT]; float linv = 0.f;
    if (MERGE) {
        const float L2E = 1.4426950408889634f;
        float mm = -3.0e38f;
        #pragma unroll
        for (int s = 0; s < NSPLIT; ++s) mm = fmaxf(mm, mp[xrow + s * 8000]);
        float ls = 0.f;
        #pragma unroll
        for (int s = 0; s < NSPLIT; ++s) {
            wgt[s] = exp2f((mp[xrow + s * 8000] - mm) * L2E);
            ls += wgt[s] * lp[xrow + s * 8000];
        }
        linv = 1.0f / ls;
    }
    float4 xv;
    float4 wv[4];
    {   // prefetch k0 = 0
        if (MERGE) {
            long idx = (long)xrow * 128 + xk;
            float4 a = make_float4(0.f, 0.f, 0.f, 0.f);
            #pragma unroll
            for (int s = 0; s < NSPLIT; ++s) {
                float4 p = *(const float4*)(X + (long)s * 1024000 + idx);
                a.x = fmaf(wgt[s], p.x, a.x); a.y = fmaf(wgt[s], p.y, a.y);
                a.z = fmaf(wgt[s], p.z, a.z); a.w = fmaf(wgt[s], p.w, a.w);
            }
            xv.x = a.x * linv; xv.y = a.y * linv; xv.z = a.z * linv; xv.w = a.w * linv;
        } else xv = *(const float4*)(X + (long)xrow * K + xk);
        if (RELU_IN) { xv.x = fmaxf(xv.x,0.f); xv.y = fmaxf(xv.y,0.f);
                       xv.z = fmaxf(xv.z,0.f); xv.w = fmaxf(xv.w,0.f); }
        #pragma unroll
        for (int u = 0; u < 4; ++u) {
            int s = t + u * 256, r = s >> 5, cb = (s & 31) << 2;
            wv[u] = *(const float4*)(W + (long)r * 128 + cb);
        }
    }
    float acc[4][4] = {};
    for (int k0 = 0; k0 < K; k0 += 32) {
        Xt[xk+0][xr] = xv.x; Xt[xk+1][xr] = xv.y; Xt[xk+2][xr] = xv.z; Xt[xk+3][xr] = xv.w;
        #pragma unroll
        for (int u = 0; u < 4; ++u) {
            int s = t + u * 256, r = s >> 5, cb = (s & 31) << 2;
            *(float4*)&Ws[r][cb] = wv[u];
        }
        __syncthreads();
        if (k0 + 32 < K) {   // prefetch next tiles; latency hidden under compute
            int kn = k0 + 32;
            if (MERGE) {
                long idx = (long)xrow * 128 + kn + xk;
                float4 a = make_float4(0.f, 0.f, 0.f, 0.f);
                #pragma unroll
                for (int s = 0; s < NSPLIT; ++s) {
                    float4 p = *(const float4*)(X + (long)s * 1024000 + idx);
                    a.x = fmaf(wgt[s], p.x, a.x); a.y = fmaf(wgt[s], p.y, a.y);
                    a.z = fmaf(wgt[s], p.z, a.z); a.w = fmaf(wgt[s], p.w, a.w);
                }
                xv.x = a.x * linv; xv.y = a.y * linv; xv.z = a.z * linv; xv.w = a.w * linv;
            } else xv = *(const float4*)(X + (long)xrow * K + kn + xk);
            if (RELU_IN) { xv.x = fmaxf(xv.x,0.f); xv.y = fmaxf(xv.y,0.f);
                           xv.z = fmaxf(xv.z,0.f); xv.w = fmaxf(xv.w,0.f); }
            #pragma unroll
            for (int u = 0; u < 4; ++u) {
                int s = t + u * 256, r = s >> 5, cb = (s & 31) << 2;
                wv[u] = *(const float4*)(W + (long)(kn + r) * 128 + cb);
            }
        }
        #pragma unroll
        for (int kk = 0; kk < 32; ++kk) {
            float4 w4 = *(const float4*)&Ws[kk][c0];
            float4 x4 = *(const float4*)&Xt[kk][r0];
            acc[0][0] = fmaf(x4.x, w4.x, acc[0][0]); acc[0][1] = fmaf(x4.x, w4.y, acc[0][1]);
            acc[0][2] = fmaf(x4.x, w4.z, acc[0][2]); acc[0][3] = fmaf(x4.x, w4.w, acc[0][3]);
            acc[1][0] = fmaf(x4.y, w4.x, acc[1][0]); acc[1][1] = fmaf(x4.y, w4.y, acc[1][1]);
            acc[1][2] = fmaf(x4.y, w4.z, acc[1][2]); acc[1][3] = fmaf(x4.y, w4.w, acc[1][3]);
            acc[2][0] = fmaf(x4.z, w4.x, acc[2][0]); acc[2][1] = fmaf(x4.z, w4.y, acc[2][1]);
            acc[2][2] = fmaf(x4.z, w4.z, acc[2][2]); acc[2][3] = fmaf(x4.z, w4.w, acc[2][3]);
            acc[3][0] = fmaf(x4.w, w4.x, acc[3][0]); acc[3][1] = fmaf(x4.w, w4.y, acc[3][1]);
            acc[3][2] = fmaf(x4.w, w4.z, acc[3][2]); acc[3][3] = fmaf(x4.w, w4.w, acc[3][3]);
        }
        __syncthreads();
    }
    float4 bv = *(const float4*)(bias + c0);
    #pragma unroll
    for (int i = 0; i < 4; ++i) {
        int row = rowbase + r0 + i;
        float4 o;
        o.x = acc[i][0] + bv.x; o.y = acc[i][1] + bv.y;
        o.z = acc[i][2] + bv.z; o.w = acc[i][3] + bv.w;
        *(float4*)(Y + (long)row * 128 + c0) = o;
    }
}

// ---------------- dual-output K|V GEMM body (32-row, 256 cols, 4x8 per thread) ----------------
__device__ __forceinline__ void kv_body(const float* __restrict__ X,
                                        const float* __restrict__ Wk, const float* __restrict__ Wv,
                                        const float* __restrict__ bk, const float* __restrict__ bv,
                                        float* __restrict__ Yk, float* __restrict__ Yv, int rowbase)
{
    __shared__ __align__(16) float Ws2[32][256];
    __shared__ __align__(16) float Xt2[32][36];
    const int t  = threadIdx.x;
    const int r0 = (t >> 5) * 4;
    const int c0 = (t & 31) * 4;
    const int xr = t >> 3, xk = (t & 7) << 2;
    const int xrow = rowbase + xr;
    float4 xv = *(const float4*)(X + (long)xrow * 128 + xk);
    float4 wv[8];
    #pragma unroll
    for (int u = 0; u < 8; ++u) {
        int s = t + u * 256, r = s >> 6, cb = (s & 63) << 2;
        wv[u] = (cb < 128) ? *(const float4*)(Wk + (long)r * 128 + cb)
                           : *(const float4*)(Wv + (long)r * 128 + cb - 128);
    }
    float ak[4][4] = {}, av[4][4] = {};
    for (int k0 = 0; k0 < 128; k0 += 32) {
        Xt2[xk+0][xr] = xv.x; Xt2[xk+1][xr] = xv.y; Xt2[xk+2][xr] = xv.z; Xt2[xk+3][xr] = xv.w;
        #pragma unroll
        for (int u = 0; u < 8; ++u) {
            int s = t + u * 256, r = s >> 6, cb = (s & 63) << 2;
            *(float4*)&Ws2[r][cb] = wv[u];
        }
        __syncthreads();
        if (k0 + 32 < 128) {
            int kn = k0 + 32;
            xv = *(const float4*)(X + (long)xrow * 128 + kn + xk);
            #pragma unroll
            for (int u = 0; u < 8; ++u) {
                int s = t + u * 256, r = s >> 6, cb = (s & 63) << 2;
                wv[u] = (cb < 128) ? *(const float4*)(Wk + (long)(kn + r) * 128 + cb)
                                   : *(const float4*)(Wv + (long)(kn + r) * 128 + cb - 128);
            }
        }
        #pragma unroll
        for (int kk = 0; kk < 32; ++kk) {
            float4 x4 = *(const float4*)&Xt2[kk][r0];
            float4 k4 = *(const float4*)&Ws2[kk][c0];
            float4 v4 = *(const float4*)&Ws2[kk][128 + c0];
            #pragma unroll
            for (int i = 0; i < 4; ++i) {
                float xi = (i==0)?x4.x:(i==1)?x4.y:(i==2)?x4.z:x4.w;
                ak[i][0] = fmaf(xi, k4.x, ak[i][0]); ak[i][1] = fmaf(xi, k4.y, ak[i][1]);
                ak[i][2] = fmaf(xi, k4.z, ak[i][2]); ak[i][3] = fmaf(xi, k4.w, ak[i][3]);
                av[i][0] = fmaf(xi, v4.x, av[i][0]); av[i][1] = fmaf(xi, v4.y, av[i][1]);
                av[i][2] = fmaf(xi, v4.z, av[i][2]); av[i][3] = fmaf(xi, v4.w, av[i][3]);
            }
        }
        __syncthreads();
    }
    float4 bk4 = *(const float4*)(bk + c0);
    float4 bv4 = *(const float4*)(bv + c0);
    #pragma unroll
    for (int i = 0; i < 4; ++i) {
        int row = rowbase + r0 + i;
        float4 ok, ov;
        ok.x = ak[i][0]+bk4.x; ok.y = ak[i][1]+bk4.y; ok.z = ak[i][2]+bk4.z; ok.w = ak[i][3]+bk4.w;
        ov.x = av[i][0]+bv4.x; ov.y = av[i][1]+bv4.y; ov.z = av[i][2]+bv4.z; ov.w = av[i][3]+bv4.w;
        *(float4*)(Yk + (long)row * 128 + c0) = ok;
        *(float4*)(Yv + (long)row * 128 + c0) = ov;
    }
}

// ---------------- pre0: W' = emb_w @ wq_w (blocks 0-9), b' = emb_b@wq_w + wq_b (block 10) ----
__global__ __launch_bounds__(256) void pre0_k(const float* __restrict__ emb_w, const float* __restrict__ emb_b,
                                              const float* __restrict__ wq_w, const float* __restrict__ wq_b,
                                              const float* __restrict__ zeros,
                                              float* __restrict__ Wp, float* __restrict__ bp)
{
    if (blockIdx.x == 10) {
        int n = threadIdx.x;
        if (n < 128) {
            float a0 = 0.f, a1 = 0.f, a2 = 0.f, a3 = 0.f;
            for (int k = 0; k < 128; k += 4) {
                a0 = fmaf(emb_b[k+0], wq_w[(k+0)*128 + n], a0);
                a1 = fmaf(emb_b[k+1], wq_w[(k+1)*128 + n], a1);
                a2 = fmaf(emb_b[k+2], wq_w[(k+2)*128 + n], a2);
                a3 = fmaf(emb_b[k+3], wq_w[(k+3)*128 + n], a3);
            }
            bp[n] = (a0 + a1) + (a2 + a3) + wq_b[n];
        }
        return;
    }
    gemm_body<false,false>(emb_w, nullptr, nullptr, wq_w, zeros, Wp, 128, blockIdx.x * 32);
}

// ---------------- qkv: Q gemm (0-249, K=320) + K/V dual gemm (250-499) ----------------
__global__ __launch_bounds__(256) void qkv_k(const float* __restrict__ PE, const float* __restrict__ Wp,
                                             const float* __restrict__ bp, const float* __restrict__ PFX,
                                             const float* __restrict__ wk_w, const float* __restrict__ wv_w,
                                             const float* __restrict__ wk_b, const float* __restrict__ wv_b,
                                             float* __restrict__ Qo, float* __restrict__ Ko, float* __restrict__ Vo)
{
    if (blockIdx.x < 250)
        gemm_body<false,false>(PE, nullptr, nullptr, Wp, bp, Qo, 320, blockIdx.x * 32);
    else
        kv_body(PFX, wk_w, wv_w, wk_b, wv_b, Ko, Vo, (blockIdx.x - 250) * 32);
}

// ---------------- wojc: wo gemm w/ 5-way split-merge (0-249) + jc gemm (250-265) ----------------
__global__ __launch_bounds__(256) void wojc_k(const float* __restrict__ Opart, const float* __restrict__ mp,
                                              const float* __restrict__ lp, const float* __restrict__ wo_w,
                                              const float* __restrict__ wo_b, float* __restrict__ Att,
                                              const float* __restrict__ CF, const float* __restrict__ jc_w,
                                              const float* __restrict__ jc_b, float* __restrict__ Cj)
{
    if (blockIdx.x < 250)
        gemm_body<false,true>(Opart, mp, lp, wo_w, wo_b, Att, 128, blockIdx.x * 32);
    else
        gemm_body<true,false>(CF, nullptr, nullptr, jc_w, jc_b, Cj, 128, (blockIdx.x - 250) * 32);
}

// ---------------- jp gemm ----------------
__global__ __launch_bounds__(256) void jp_k(const float* __restrict__ Att, const float* __restrict__ jp_w,
                                            const float* __restrict__ jp_b, float* __restrict__ P)
{
    gemm_body<true,false>(Att, nullptr, nullptr, jp_w, jp_b, P, 128, blockIdx.x * 32);
}

// ---------------- flash attention v5: TQ=64, TK=64, sp=5 splits, 256 threads, 4r x 4c ----------
// Grid 16 x 5 x 8 = 640 blocks = 2.5 blocks/CU (LDS 51.2 KB allows 3). Q read from global
// (16-way lane broadcast, L1-served). K,V register-prefetched across barriers. Pt-transposed P.
__global__ __launch_bounds__(256) void flash5_k(const float* __restrict__ Q, const float* __restrict__ Kg,
                                                const float* __restrict__ Vg, float* __restrict__ Opart,
                                                float* __restrict__ mpart, float* __restrict__ lpart)
{
    __shared__ __align__(16) float KVs[64][132];
    __shared__ __align__(16) float Pt[64][68];
    const int t  = threadIdx.x;
    const int rg = t >> 4;        // 0..15 -> rows 4rg..4rg+3
    const int cl = t & 15;        // cols cl+16j
    const int qt = blockIdx.x, sp = blockIdx.y, b = blockIdx.z;
    const int q0 = qt * 64;
    const int kt0 = (sp * 16) / NSPLIT;           // 0,3,6,9,12
    const int kt1 = ((sp + 1) * 16) / NSPLIT;     // 3,6,9,12,16
    const float SCALE = 0.08838834764831845f;   // 1/sqrt(128)
    const float L2E   = 1.4426950408889634f;
    const float* Qb = Q + ((long)b * LP + q0 + 4 * rg) * 128;   // rows >=LP read in-ws garbage, masked at store

    float m_i[4] = {-3.0e38f,-3.0e38f,-3.0e38f,-3.0e38f};
    float l_i[4] = {0.f,0.f,0.f,0.f};
    float Oa[4][8] = {};
    float4 kreg[8], vreg[8];
    {   // prologue: K prefetch for first kt
        const int key0 = kt0 * 64;
        #pragma unroll
        for (int u = 0; u < 8; ++u) {
            int s = t + u * 256, r = s >> 5, cb = (s & 31) << 2;
            kreg[u] = make_float4(0.f,0.f,0.f,0.f);
            if (key0 + r < LP) kreg[u] = *(const float4*)(Kg + ((long)b * LP + key0 + r) * 128 + cb);
        }
    }
    for (int kt = kt0; kt < kt1; ++kt) {
        const int key0 = kt * 64;
        __syncthreads();                               // (A) prev PV done with KVs/Pt
        #pragma unroll
        for (int u = 0; u < 8; ++u) {                  // K regs -> LDS
            int s = t + u * 256, r = s >> 5, cb = (s & 31) << 2;
            KVs[r][cb] = kreg[u].x; KVs[r][cb+1] = kreg[u].y;
            KVs[r][cb+2] = kreg[u].z; KVs[r][cb+3] = kreg[u].w;
        }
        __syncthreads();                               // (B) K visible
        #pragma unroll
        for (int u = 0; u < 8; ++u) {                  // V prefetch (drains under QK)
            int s = t + u * 256, r = s >> 5, cb = (s & 31) << 2;
            vreg[u] = make_float4(0.f,0.f,0.f,0.f);
            if (key0 + r < LP) vreg[u] = *(const float4*)(Vg + ((long)b * LP + key0 + r) * 128 + cb);
        }
        float sacc[4][4] = {};
        #pragma unroll 4
        for (int d4 = 0; d4 < 32; ++d4) {
            float4 q0v = *(const float4*)(Qb + 0 * 128 + (d4 << 2));
            float4 q1v = *(const float4*)(Qb + 1 * 128 + (d4 << 2));
            float4 q2v = *(const float4*)(Qb + 2 * 128 + (d4 << 2));
            float4 q3v = *(const float4*)(Qb + 3 * 128 + (d4 << 2));
            #pragma unroll
            for (int j = 0; j < 4; ++j) {
                float4 kv = *(const float4*)&KVs[cl + (j << 4)][d4 << 2];
                sacc[0][j] += q0v.x*kv.x + q0v.y*kv.y + q0v.z*kv.z + q0v.w*kv.w;
                sacc[1][j] += q1v.x*kv.x + q1v.y*kv.y + q1v.z*kv.z + q1v.w*kv.w;
                sacc[2][j] += q2v.x*kv.x + q2v.y*kv.y + q2v.z*kv.z + q2v.w*kv.w;
                sacc[3][j] += q3v.x*kv.x + q3v.y*kv.y + q3v.z*kv.z + q3v.w*kv.w;
            }
        }
        #pragma unroll
        for (int j = 0; j < 4; ++j) {                  // scale + key mask
            bool valid = (key0 + cl + (j << 4)) < LP;
            #pragma unroll
            for (int i = 0; i < 4; ++i) {
                float sv = sacc[i][j] * SCALE;
                sacc[i][j] = valid ? sv : -3.0e38f;
            }
        }
        #pragma unroll
        for (int i = 0; i < 4; ++i) {                  // online softmax (16-lane row groups)
            float tm = fmaxf(fmaxf(sacc[i][0], sacc[i][1]), fmaxf(sacc[i][2], sacc[i][3]));
            tm = fmaxf(tm, __shfl_xor(tm, 1));
            tm = fmaxf(tm, __shfl_xor(tm, 2));
            tm = fmaxf(tm, __shfl_xor(tm, 4));
            tm = fmaxf(tm, __shfl_xor(tm, 8));
            float mnew = fmaxf(m_i[i], tm);
            float alpha = exp2f((m_i[i] - mnew) * L2E);
            float ps = 0.f;
            #pragma unroll
            for (int j = 0; j < 4; ++j) {
                float p = exp2f((sacc[i][j] - mnew) * L2E);
                sacc[i][j] = p;
                ps += p;
            }
            ps += __shfl_xor(ps, 1);
            ps += __shfl_xor(ps, 2);
            ps += __shfl_xor(ps, 4);
            ps += __shfl_xor(ps, 8);
            l_i[i] = l_i[i] * alpha + ps;
            m_i[i] = mnew;
            #pragma unroll
            for (int j = 0; j < 8; ++j) Oa[i][j] *= alpha;
        }
        __syncthreads();                               // (C) all QK reads of KVs done
        #pragma unroll
        for (int u = 0; u < 8; ++u) {                  // V regs -> LDS (overwrite K)
            int s = t + u * 256, r = s >> 5, cb = (s & 31) << 2;
            KVs[r][cb] = vreg[u].x; KVs[r][cb+1] = vreg[u].y;
            KVs[r][cb+2] = vreg[u].z; KVs[r][cb+3] = vreg[u].w;
        }
        #pragma unroll
        for (int j = 0; j < 4; ++j)                    // P -> Pt[c][rows]
            *(float4*)&Pt[cl + (j << 4)][4 * rg] =
                make_float4(sacc[0][j], sacc[1][j], sacc[2][j], sacc[3][j]);
        __syncthreads();                               // (D) V + Pt visible
        if (kt + 1 < kt1) {                            // K prefetch kt+1 (drains under PV)
            const int kn0 = (kt + 1) * 64;
            #pragma unroll
            for (int u = 0; u < 8; ++u) {
                int s = t + u * 256, r = s >> 5, cb = (s & 31) << 2;
                kreg[u] = make_float4(0.f,0.f,0.f,0.f);
                if (kn0 + r < LP) kreg[u] = *(const float4*)(Kg + ((long)b * LP + kn0 + r) * 128 + cb);
            }
        }
        #pragma unroll 2
        for (int c = 0; c < 64; ++c) {                 // PV
            float4 p4 = *(const float4*)&Pt[c][4 * rg];
            float4 va = *(const float4*)&KVs[c][4 * cl];
            float4 vb = *(const float4*)&KVs[c][64 + 4 * cl];
            Oa[0][0]=fmaf(p4.x,va.x,Oa[0][0]); Oa[0][1]=fmaf(p4.x,va.y,Oa[0][1]);
            Oa[0][2]=fmaf(p4.x,va.z,Oa[0][2]); Oa[0][3]=fmaf(p4.x,va.w,Oa[0][3]);
            Oa[0][4]=fmaf(p4.x,vb.x,Oa[0][4]); Oa[0][5]=fmaf(p4.x,vb.y,Oa[0][5]);
            Oa[0][6]=fmaf(p4.x,vb.z,Oa[0][6]); Oa[0][7]=fmaf(p4.x,vb.w,Oa[0][7]);
            Oa[1][0]=fmaf(p4.y,va.x,Oa[1][0]); Oa[1][1]=fmaf(p4.y,va.y,Oa[1][1]);
            Oa[1][2]=fmaf(p4.y,va.z,Oa[1][2]); Oa[1][3]=fmaf(p4.y,va.w,Oa[1][3]);
            Oa[1][4]=fmaf(p4.y,vb.x,Oa[1][4]); Oa[1][5]=fmaf(p4.y,vb.y,Oa[1][5]);
            Oa[1][6]=fmaf(p4.y,vb.z,Oa[1][6]); Oa[1][7]=fmaf(p4.y,vb.w,Oa[1][7]);
            Oa[2][0]=fmaf(p4.z,va.x,Oa[2][0]); Oa[2][1]=fmaf(p4.z,va.y,Oa[2][1]);
            Oa[2][2]=fmaf(p4.z,va.z,Oa[2][2]); Oa[2][3]=fmaf(p4.z,va.w,Oa[2][3]);
            Oa[2][4]=fmaf(p4.z,vb.x,Oa[2][4]); Oa[2][5]=fmaf(p4.z,vb.y,Oa[2][5]);
            Oa[2][6]=fmaf(p4.z,vb.z,Oa[2][6]); Oa[2][7]=fmaf(p4.z,vb.w,Oa[2][7]);
            Oa[3][0]=fmaf(p4.w,va.x,Oa[3][0]); Oa[3][1]=fmaf(p4.w,va.y,Oa[3][1]);
            Oa[3][2]=fmaf(p4.w,va.z,Oa[3][2]); Oa[3][3]=fmaf(p4.w,va.w,Oa[3][3]);
            Oa[3][4]=fmaf(p4.w,vb.x,Oa[3][4]); Oa[3][5]=fmaf(p4.w,vb.y,Oa[3][5]);
            Oa[3][6]=fmaf(p4.w,vb.z,Oa[3][6]); Oa[3][7]=fmaf(p4.w,vb.w,Oa[3][7]);
        }
    }
    #pragma unroll
    for (int i = 0; i < 4; ++i) {
        int row = q0 + 4 * rg + i;
        if (row < LP) {
            long base = ((long)sp * 1024000) + ((long)b * LP + row) * 128;
            *(float4*)(Opart + base + 4 * cl)      = make_float4(Oa[i][0], Oa[i][1], Oa[i][2], Oa[i][3]);
            *(float4*)(Opart + base + 64 + 4 * cl) = make_float4(Oa[i][4], Oa[i][5], Oa[i][6], Oa[i][7]);
            if (cl == 0) {
                mpart[(long)sp * 8000 + b * LP + row] = m_i[i];
                lpart[(long)sp * 8000 + b * LP + row] = l_i[i];
            }
        }
    }
}

// -------- fused: A = sigmoid(P C^T) in LDS + Asum + tanh outer-product reduce (16-row tiles) -----
__global__ __launch_bounds__(256) void sigcp_k(const float* __restrict__ P, const float* __restrict__ Cj,
                                               const float* __restrict__ pf, const float* __restrict__ cf,
                                               float* __restrict__ Asum, float* __restrict__ cpe)
{
    __shared__ __align__(16) float Psh[16][132];
    __shared__ __align__(16) float Csh[64][132];
    __shared__ float Ash[16][64];
    __shared__ float red[256];
    const int t  = threadIdx.x;
    const int tr = t >> 4, tc = t & 15;     // 1 row x 4 cols
    const int i0 = blockIdx.x * 16;
    const int b  = blockIdx.y;
    #pragma unroll
    for (int u = 0; u < 2; ++u) {
        int s = t + u * 256, r = s >> 5, cb = (s & 31) << 2;
        float4 v = make_float4(0.f,0.f,0.f,0.f);
        if (i0 + r < LP) v = *(const float4*)(P + ((long)b * LP + i0 + r) * 128 + cb);
        Psh[r][cb] = v.x; Psh[r][cb+1] = v.y; Psh[r][cb+2] = v.z; Psh[r][cb+3] = v.w;
    }
    #pragma unroll
    for (int u = 0; u < 8; ++u) {
        int s = t + u * 256, r = s >> 5, cb = (s & 31) << 2;
        float4 v = *(const float4*)(Cj + ((long)b * NCMP + r) * 128 + cb);
        Csh[r][cb] = v.x; Csh[r][cb+1] = v.y; Csh[r][cb+2] = v.z; Csh[r][cb+3] = v.w;
    }
    __syncthreads();
    float sacc[4] = {};
    #pragma unroll 4
    for (int d4 = 0; d4 < 32; ++d4) {
        float4 p0 = *(const float4*)&Psh[tr][d4 << 2];
        #pragma unroll
        for (int j = 0; j < 4; ++j) {
            float4 cv = *(const float4*)&Csh[tc + (j << 4)][d4 << 2];
            sacc[j] += p0.x*cv.x + p0.y*cv.y + p0.z*cv.z + p0.w*cv.w;
        }
    }
    const float L2E = 1.4426950408889634f;
    float lsum = 0.f;
    {
        int gi = i0 + tr;
        #pragma unroll
        for (int j = 0; j < 4; ++j) {
            float sg = rcp_fast(1.f + exp2f(-sacc[j] * L2E));
            if (gi < LP) { Ash[tr][tc + (j << 4)] = sg; lsum += sg; }
        }
    }
    red[t] = lsum;
    __syncthreads();
    for (int off = 128; off > 0; off >>= 1) {
        if (t < off) red[t] += red[t + off];
        __syncthreads();
    }
    if (t == 0) atomicAdd(Asum + b, red[0]);
    __syncthreads();
    #pragma unroll
    for (int u = 0; u < 8; ++u) {                      // reload Csh with raw compound feats
        int s = t + u * 256, r = s >> 5, cb = (s & 31) << 2;
        float4 v = *(const float4*)(cf + ((long)b * NCMP + r) * 128 + cb);
        Csh[r][cb] = v.x; Csh[r][cb+1] = v.y; Csh[r][cb+2] = v.z; Csh[r][cb+3] = v.w;
    }
    __syncthreads();
    const float TWO_L2E = 2.8853900817779268f;   // 2*log2(e)
    const int d  = t & 127;
    const int kh = t >> 7;
    const int iiN = (LP - i0 < 16) ? (LP - i0) : 16;
    float acc = 0.f;
    for (int ii = 0; ii < iiN; ++ii) {
        float pv  = pf[((long)b * LP + i0 + ii) * 128 + d];
        float ptl = pv * TWO_L2E;
        #pragma unroll
        for (int kk = 0; kk < 32; ++kk) {
            int k = (kh << 5) + kk;
            float e  = exp2f(ptl * Csh[k][d]);          // exp(2x)
            float th = 1.f - 2.f * rcp_fast(e + 1.f);   // tanh(x)
            acc = fmaf(th, Ash[ii][k], acc);
        }
    }
    red[t] = acc;
    __syncthreads();
    if (t < 128) atomicAdd(cpe + (long)b * 128 + t, red[t] + red[t + 128]);
}

// ---------------- classifier head ----------------
__global__ __launch_bounds__(256) void c1h_k(const float* __restrict__ cpe, const float* __restrict__ Asum,
                                             const float* __restrict__ W, const float* __restrict__ bias,
                                             float* __restrict__ h1)
{
    __shared__ float sc[8][128];
    const int t = threadIdx.x;
    #pragma unroll
    for (int u = 0; u < 4; ++u) {
        int idx = t + u * 256;
        sc[idx >> 7][idx & 127] = cpe[idx] * rcp_fast(Asum[idx >> 7]);
    }
    __syncthreads();
    const int b = t >> 5, n = blockIdx.x * 32 + (t & 31);
    float a0 = 0.f, a1 = 0.f, a2 = 0.f, a3 = 0.f;
    #pragma unroll 8
    for (int k = 0; k < 128; k += 4) {
        a0 = fmaf(sc[b][k+0], W[(long)(k+0)*1024 + n], a0);
        a1 = fmaf(sc[b][k+1], W[(long)(k+1)*1024 + n], a1);
        a2 = fmaf(sc[b][k+2], W[(long)(k+2)*1024 + n], a2);
        a3 = fmaf(sc[b][k+3], W[(long)(k+3)*1024 + n], a3);
    }
    h1[b * 1024 + n] = fmaxf((a0 + a1) + (a2 + a3) + bias[n], 0.f);
}

__global__ __launch_bounds__(256) void c2_part_k(const float* __restrict__ in, const float* __restrict__ W,
                                                 float* __restrict__ part)
{
    __shared__ float ins[8][16];
    const int t = threadIdx.x, ks = blockIdx.x, k0 = ks * 16;
    if (t < 128) {
        int b = t >> 4, kk = t & 15;
        ins[b][kk] = in[b * 1024 + k0 + kk];
    }
    __syncthreads();
    const int n = (t & 63) * 4 + (t >> 6) * 256;
    float4 acc[8] = {};
    #pragma unroll
    for (int kk = 0; kk < 16; ++kk) {
        float4 w4 = *(const float4*)(W + (long)(k0 + kk) * 1024 + n);
        #pragma unroll
        for (int b = 0; b < 8; ++b) {
            float s = ins[b][kk];
            acc[b].x = fmaf(s, w4.x, acc[b].x); acc[b].y = fmaf(s, w4.y, acc[b].y);
            acc[b].z = fmaf(s, w4.z, acc[b].z); acc[b].w = fmaf(s, w4.w, acc[b].w);
        }
    }
    #pragma unroll
    for (int b = 0; b < 8; ++b)
        *(float4*)(part + ((long)(ks * 8 + b)) * 1024 + n) = acc[b];
}

__global__ __launch_bounds__(256) void c3m_k(const float* __restrict__ part2, const float* __restrict__ c2_b,
                                             const float* __restrict__ c3_w, const float* __restrict__ c3_b,
                                             const float* __restrict__ c4_w, const float* __restrict__ c4_b,
                                             float* __restrict__ out)
{
    __shared__ float Hs[1024];
    __shared__ float red[256];
    const int t = threadIdx.x, b = blockIdx.x;
    float4 acc4 = make_float4(0.f,0.f,0.f,0.f);
    #pragma unroll 4
    for (int ks = 0; ks < 64; ++ks) {
        float4 p = *(const float4*)(part2 + ((long)(ks * 8 + b)) * 1024 + t * 4);
        acc4.x += p.x; acc4.y += p.y; acc4.z += p.z; acc4.w += p.w;
    }
    {
        float4 bb = *(const float4*)(c2_b + t * 4);
        Hs[t*4+0] = fmaxf(acc4.x + bb.x, 0.f);
        Hs[t*4+1] = fmaxf(acc4.y + bb.y, 0.f);
        Hs[t*4+2] = fmaxf(acc4.z + bb.z, 0.f);
        Hs[t*4+3] = fmaxf(acc4.w + bb.w, 0.f);
    }
    __syncthreads();
    float a0 = 0.f, a1 = 0.f, a2 = 0.f, a3 = 0.f;
    #pragma unroll 8
    for (int k = 0; k < 1024; k += 4) {
        a0 = fmaf(Hs[k+0], c3_w[(long)(k+0)*256 + t], a0);
        a1 = fmaf(Hs[k+1], c3_w[(long)(k+1)*256 + t], a1);
        a2 = fmaf(Hs[k+2], c3_w[(long)(k+2)*256 + t], a2);
        a3 = fmaf(Hs[k+3], c3_w[(long)(k+3)*256 + t], a3);
    }
    float h3v = fmaxf((a0 + a1) + (a2 + a3) + c3_b[t], 0.f);
    red[t] = h3v * c4_w[t];
    __syncthreads();
    for (int off = 128; off > 0; off >>= 1) {
        if (t < off) red[t] += red[t + off];
        __syncthreads();
    }
    if (t == 0) out[b] = red[0] + c4_b[0];
}

extern "C" void kernel_launch(void* const* d_in, const int* in_sizes, int n_in,
                              void* d_out, int out_size, void* d_ws, size_t ws_size,
                              hipStream_t stream)
{
    const float* PE   = (const float*)d_in[0];
    const float* PFX  = (const float*)d_in[1];
    const float* CF   = (const float*)d_in[2];
    const float* emb_w = (const float*)d_in[3];  const float* emb_b = (const float*)d_in[4];
    const float* wq_w  = (const float*)d_in[5];  const float* wq_b  = (const float*)d_in[6];
    const float* wk_w  = (const float*)d_in[7];  const float* wk_b  = (const float*)d_in[8];
    const float* wv_w  = (const float*)d_in[9];  const float* wv_b  = (const float*)d_in[10];
    const float* wo_w  = (const float*)d_in[11]; const float* wo_b  = (const float*)d_in[12];
    const float* jp_w  = (const float*)d_in[13]; const float* jp_b  = (const float*)d_in[14];
    const float* jc_w  = (const float*)d_in[15]; const float* jc_b  = (const float*)d_in[16];
    const float* c1_w  = (const float*)d_in[17]; const float* c1_b  = (const float*)d_in[18];
    const float* c2_w  = (const float*)d_in[19]; const float* c2_b  = (const float*)d_in[20];
    const float* c3_w  = (const float*)d_in[21]; const float* c3_b  = (const float*)d_in[22];
    const float* c4_w  = (const float*)d_in[23]; const float* c4_b  = (const float*)d_in[24];

    float* ws     = (float*)d_ws;
    float* bufQ   = ws;                    // 1,024,000 (Q; later jp-out alias; later c2 partials alias)
    float* bufK   = bufQ   + 1024000;      // 1,024,000
    float* bufV   = bufK   + 1024000;      // 1,024,000
    float* bufC   = bufV   + 1024000;      //    65,536
    float* Opart  = bufC   + 65536;        // 5,120,000 (5-way flash partials; slab4 doubles as Att)
    float* mpart  = Opart  + 5120000;      //    40,000
    float* lpart  = mpart  + 40000;        //    40,000
    float* Asum   = lpart  + 40000;        //         8
    float* cpe    = Asum   + 8;            //     1,024
    float* zeros  = cpe    + 1024;         //       128
    float* bprime = zeros  + 128;          //       128
    float* bufWp  = bprime + 128;          //    40,960  (emb_w @ wq_w)
    float* h1     = bufWp  + 40960;        //     8,192
    // Aliases: Att shares Opart slab 4 (each wojc block reads exactly the rows it
    // later writes, all reads precede stores). bufP/c2-partials share bufQ.
    float* bufAtt = Opart  + 4 * 1024000;
    float* bufP   = bufQ;
    float* part2  = bufQ;
    // total ~8.39M floats = ~33.6 MB (same footprint as round 6)

    hipMemsetAsync(Asum, 0, (8 + 1024 + 128) * sizeof(float), stream);   // Asum, cpe, zeros

    pre0_k<<<11, 256, 0, stream>>>(emb_w, emb_b, wq_w, wq_b, zeros, bufWp, bprime);
    qkv_k<<<500, 256, 0, stream>>>(PE, bufWp, bprime, PFX, wk_w, wv_w, wk_b, wv_b,
                                   bufQ, bufK, bufV);
    flash5_k<<<dim3(16, NSPLIT, 8), 256, 0, stream>>>(bufQ, bufK, bufV, Opart, mpart, lpart);
    wojc_k<<<266, 256, 0, stream>>>(Opart, mpart, lpart, wo_w, wo_b, bufAtt,
                                    CF, jc_w, jc_b, bufC);
    jp_k<<<250, 256, 0, stream>>>(bufAtt, jp_w, jp_b, bufP);
    sigcp_k<<<dim3(63, 8), 256, 0, stream>>>(bufP, bufC, bufAtt, CF, Asum, cpe);
    c1h_k<<<32, 256, 0, stream>>>(cpe, Asum, c1_w, c1_b, h1);
    c2_part_k<<<64, 256, 0, stream>>>(h1, c2_w, part2);
    c3m_k<<<8, 256, 0, stream>>>(part2, c2_b, c3_w, c3_b, c4_w, c4_b, (float*)d_out);
}

// Round 8
// 336.436 us; speedup vs baseline: 1.1580x; 1.1580x over previous
//
#include <hip/hip_runtime.h>
#include <hip/hip_bf16.h>
#include <math.h>

#define LP 1000
#define NCMP 64

__device__ __forceinline__ float rcp_fast(float x) { return __builtin_amdgcn_rcpf(x); }

// ---------------- GEMM body: Y[M,128] = op(X)[M,K] @ W[K,128] + b ----------------
// 32-row tile, 256 threads, thread = 4x4, X transposed in LDS, software-pipelined.
template<bool RELU_IN>
__device__ __forceinline__ void gemm_body(const float* X, const float* W, const float* __restrict__ bias,
                                          float* Y, int K, int rowbase)
{
    __shared__ __align__(16) float Ws[32][128];
    __shared__ __align__(16) float Xt[32][36];
    const int t  = threadIdx.x;
    const int r0 = (t >> 5) * 4;
    const int c0 = (t & 31) * 4;
    const int xr = t >> 3, xk = (t & 7) << 2;
    const int xrow = rowbase + xr;
    float4 xv = *(const float4*)(X + (long)xrow * K + xk);
    float4 wv[4];
    #pragma unroll
    for (int u = 0; u < 4; ++u) {
        int s = t + u * 256, r = s >> 5, cb = (s & 31) << 2;
        wv[u] = *(const float4*)(W + (long)r * 128 + cb);
    }
    float acc[4][4] = {};
    for (int k0 = 0; k0 < K; k0 += 32) {
        float4 xs = xv;
        if (RELU_IN) { xs.x = fmaxf(xs.x,0.f); xs.y = fmaxf(xs.y,0.f);
                       xs.z = fmaxf(xs.z,0.f); xs.w = fmaxf(xs.w,0.f); }
        Xt[xk+0][xr] = xs.x; Xt[xk+1][xr] = xs.y; Xt[xk+2][xr] = xs.z; Xt[xk+3][xr] = xs.w;
        #pragma unroll
        for (int u = 0; u < 4; ++u) {
            int s = t + u * 256, r = s >> 5, cb = (s & 31) << 2;
            *(float4*)&Ws[r][cb] = wv[u];
        }
        __syncthreads();
        if (k0 + 32 < K) {
            xv = *(const float4*)(X + (long)xrow * K + k0 + 32 + xk);
            #pragma unroll
            for (int u = 0; u < 4; ++u) {
                int s = t + u * 256, r = s >> 5, cb = (s & 31) << 2;
                wv[u] = *(const float4*)(W + (long)(k0 + 32 + r) * 128 + cb);
            }
        }
        #pragma unroll
        for (int kk = 0; kk < 32; ++kk) {
            float4 w4 = *(const float4*)&Ws[kk][c0];
            float4 x4 = *(const float4*)&Xt[kk][r0];
            acc[0][0] = fmaf(x4.x, w4.x, acc[0][0]); acc[0][1] = fmaf(x4.x, w4.y, acc[0][1]);
            acc[0][2] = fmaf(x4.x, w4.z, acc[0][2]); acc[0][3] = fmaf(x4.x, w4.w, acc[0][3]);
            acc[1][0] = fmaf(x4.y, w4.x, acc[1][0]); acc[1][1] = fmaf(x4.y, w4.y, acc[1][1]);
            acc[1][2] = fmaf(x4.y, w4.z, acc[1][2]); acc[1][3] = fmaf(x4.y, w4.w, acc[1][3]);
            acc[2][0] = fmaf(x4.z, w4.x, acc[2][0]); acc[2][1] = fmaf(x4.z, w4.y, acc[2][1]);
            acc[2][2] = fmaf(x4.z, w4.z, acc[2][2]); acc[2][3] = fmaf(x4.z, w4.w, acc[2][3]);
            acc[3][0] = fmaf(x4.w, w4.x, acc[3][0]); acc[3][1] = fmaf(x4.w, w4.y, acc[3][1]);
            acc[3][2] = fmaf(x4.w, w4.z, acc[3][2]); acc[3][3] = fmaf(x4.w, w4.w, acc[3][3]);
        }
        __syncthreads();
    }
    float4 bv = *(const float4*)(bias + c0);
    #pragma unroll
    for (int i = 0; i < 4; ++i) {
        int row = rowbase + r0 + i;
        float4 o;
        o.x = acc[i][0] + bv.x; o.y = acc[i][1] + bv.y;
        o.z = acc[i][2] + bv.z; o.w = acc[i][3] + bv.w;
        *(float4*)(Y + (long)row * 128 + c0) = o;
    }
}

// ---- pre0: blocks 0-9: Wp=emb_w@wq_w; 10: bp=emb_b@wq_w+wq_b;
//            11-14: Wvo=wv_w@wo_w;      15: bvo=wv_b@wo_w+wo_b ----
__global__ __launch_bounds__(256) void pre0_k(const float* __restrict__ emb_w, const float* __restrict__ emb_b,
                                              const float* __restrict__ wq_w, const float* __restrict__ wq_b,
                                              const float* __restrict__ wv_w, const float* __restrict__ wv_b,
                                              const float* __restrict__ wo_w, const float* __restrict__ wo_b,
                                              const float* __restrict__ zeros,
                                              float* __restrict__ Wp, float* __restrict__ bp,
                                              float* __restrict__ Wvo, float* __restrict__ bvo)
{
    const int bid = blockIdx.x;
    if (bid < 10) { gemm_body<false>(emb_w, wq_w, zeros, Wp, 128, bid * 32); return; }
    if (bid >= 11 && bid < 15) { gemm_body<false>(wv_w, wo_w, zeros, Wvo, 128, (bid - 11) * 32); return; }
    int n = threadIdx.x;
    if (n < 128) {
        const float* vb = (bid == 10) ? emb_b : wv_b;
        const float* Wm = (bid == 10) ? wq_w  : wo_w;
        const float* ab = (bid == 10) ? wq_b  : wo_b;
        float a0 = 0.f, a1 = 0.f, a2 = 0.f, a3 = 0.f;
        for (int k = 0; k < 128; k += 4) {
            a0 = fmaf(vb[k+0], Wm[(k+0)*128 + n], a0);
            a1 = fmaf(vb[k+1], Wm[(k+1)*128 + n], a1);
            a2 = fmaf(vb[k+2], Wm[(k+2)*128 + n], a2);
            a3 = fmaf(vb[k+3], Wm[(k+3)*128 + n], a3);
        }
        float* dst = (bid == 10) ? bp : bvo;
        dst[n] = (a0 + a1) + (a2 + a3) + ab[n];
    }
}

// ---- qkv: 0-249 Q=PE@Wp+bp (K=320); 250-499 K=PFX@wk+bk; 500-515 Cj=relu(CF)@jc+bc ----
__global__ __launch_bounds__(256) void qkv_k(const float* __restrict__ PE, const float* __restrict__ Wp,
                                             const float* __restrict__ bp, const float* __restrict__ PFX,
                                             const float* __restrict__ wk_w, const float* __restrict__ wk_b,
                                             const float* __restrict__ CF, const float* __restrict__ jc_w,
                                             const float* __restrict__ jc_b,
                                             float* __restrict__ Qo, float* __restrict__ Ko, float* __restrict__ Cj)
{
    if (blockIdx.x < 250)
        gemm_body<false>(PE, Wp, bp, Qo, 320, blockIdx.x * 32);
    else if (blockIdx.x < 500)
        gemm_body<false>(PFX, wk_w, wk_b, Ko, 128, (blockIdx.x - 250) * 32);
    else
        gemm_body<true>(CF, jc_w, jc_b, Cj, 128, (blockIdx.x - 500) * 32);
}

// ---------------- flash attention (fp32), TQ=32, TK=64, KV-split x2 — R3-proven design ----------
// V = raw PFX (Wv folded into post-GEMM). 256 threads, thread 2r x 4c. 59.4 KB LDS, 2 blk/CU.
__global__ __launch_bounds__(256) void flash_k(const float* __restrict__ Q, const float* __restrict__ Kg,
                                               const float* __restrict__ Vg, float* __restrict__ Opart,
                                               float* __restrict__ mpart, float* __restrict__ lpart)
{
    __shared__ __align__(16) float Qs[32][132];
    __shared__ __align__(16) float KVs[64][132];
    __shared__ __align__(16) float Ps[32][68];
    const int t  = threadIdx.x;
    const int tr = t >> 4;
    const int tc = t & 15;
    const int qt = blockIdx.x, sp = blockIdx.y, b = blockIdx.z;
    const int q0 = qt * 32;
    const float SCALE = 0.08838834764831845f;   // 1/sqrt(128)
    const float L2E   = 1.4426950408889634f;

    #pragma unroll
    for (int u = 0; u < 4; ++u) {
        int s = t + u * 256;
        int r = s >> 5, cb = (s & 31) << 2;
        float4 v = make_float4(0.f, 0.f, 0.f, 0.f);
        if (q0 + r < LP) v = *(const float4*)(Q + ((long)b * LP + q0 + r) * 128 + cb);
        Qs[r][cb] = v.x; Qs[r][cb + 1] = v.y; Qs[r][cb + 2] = v.z; Qs[r][cb + 3] = v.w;
    }
    float m_i[2] = { -3.0e38f, -3.0e38f };
    float l_i[2] = { 0.f, 0.f };
    float Oa[2][8] = {};

    for (int kt = sp * 8; kt < sp * 8 + 8; ++kt) {
        const int key0 = kt * 64;
        __syncthreads();
        #pragma unroll
        for (int u = 0; u < 8; ++u) {
            int s = t + u * 256;
            int r = s >> 5, cb = (s & 31) << 2;
            float4 v = make_float4(0.f, 0.f, 0.f, 0.f);
            if (key0 + r < LP) v = *(const float4*)(Kg + ((long)b * LP + key0 + r) * 128 + cb);
            KVs[r][cb] = v.x; KVs[r][cb + 1] = v.y; KVs[r][cb + 2] = v.z; KVs[r][cb + 3] = v.w;
        }
        __syncthreads();
        float sacc[2][4] = {};
        #pragma unroll 4
        for (int d4 = 0; d4 < 32; ++d4) {
            float4 q0v = *(const float4*)&Qs[2 * tr][d4 << 2];
            float4 q1v = *(const float4*)&Qs[2 * tr + 1][d4 << 2];
            #pragma unroll
            for (int j = 0; j < 4; ++j) {
                float4 kv = *(const float4*)&KVs[tc + (j << 4)][d4 << 2];
                sacc[0][j] += q0v.x * kv.x + q0v.y * kv.y + q0v.z * kv.z + q0v.w * kv.w;
                sacc[1][j] += q1v.x * kv.x + q1v.y * kv.y + q1v.z * kv.z + q1v.w * kv.w;
            }
        }
        __syncthreads();
        float4 vreg[8];
        #pragma unroll
        for (int u = 0; u < 8; ++u) {
            int s = t + u * 256;
            int r = s >> 5, cb = (s & 31) << 2;
            float4 v = make_float4(0.f, 0.f, 0.f, 0.f);
            if (key0 + r < LP) v = *(const float4*)(Vg + ((long)b * LP + key0 + r) * 128 + cb);
            vreg[u] = v;
        }
        #pragma unroll
        for (int j = 0; j < 4; ++j) {
            bool valid = (key0 + tc + (j << 4)) < LP;
            #pragma unroll
            for (int i = 0; i < 2; ++i) {
                float sv = sacc[i][j] * SCALE;
                sacc[i][j] = valid ? sv : -3.0e38f;
            }
        }
        #pragma unroll
        for (int i = 0; i < 2; ++i) {
            float tm = fmaxf(fmaxf(sacc[i][0], sacc[i][1]), fmaxf(sacc[i][2], sacc[i][3]));
            tm = fmaxf(tm, __shfl_xor(tm, 1));
            tm = fmaxf(tm, __shfl_xor(tm, 2));
            tm = fmaxf(tm, __shfl_xor(tm, 4));
            tm = fmaxf(tm, __shfl_xor(tm, 8));
            float mnew  = fmaxf(m_i[i], tm);
            float alpha = exp2f((m_i[i] - mnew) * L2E);
            float ps = 0.f;
            #pragma unroll
            for (int j = 0; j < 4; ++j) {
                float p = exp2f((sacc[i][j] - mnew) * L2E);
                Ps[2 * tr + i][tc + (j << 4)] = p;
                ps += p;
            }
            ps += __shfl_xor(ps, 1);
            ps += __shfl_xor(ps, 2);
            ps += __shfl_xor(ps, 4);
            ps += __shfl_xor(ps, 8);
            l_i[i] = l_i[i] * alpha + ps;
            m_i[i] = mnew;
            #pragma unroll
            for (int j = 0; j < 8; ++j) Oa[i][j] *= alpha;
        }
        #pragma unroll
        for (int u = 0; u < 8; ++u) {
            int s = t + u * 256;
            int r = s >> 5, cb = (s & 31) << 2;
            KVs[r][cb] = vreg[u].x; KVs[r][cb + 1] = vreg[u].y;
            KVs[r][cb + 2] = vreg[u].z; KVs[r][cb + 3] = vreg[u].w;
        }
        __syncthreads();
        #pragma unroll 2
        for (int c = 0; c < 64; ++c) {
            float4 va = *(const float4*)&KVs[c][tc << 2];
            float4 vb = *(const float4*)&KVs[c][64 + (tc << 2)];
            float p0 = Ps[2 * tr][c];
            float p1 = Ps[2 * tr + 1][c];
            Oa[0][0] = fmaf(p0, va.x, Oa[0][0]); Oa[0][1] = fmaf(p0, va.y, Oa[0][1]);
            Oa[0][2] = fmaf(p0, va.z, Oa[0][2]); Oa[0][3] = fmaf(p0, va.w, Oa[0][3]);
            Oa[0][4] = fmaf(p0, vb.x, Oa[0][4]); Oa[0][5] = fmaf(p0, vb.y, Oa[0][5]);
            Oa[0][6] = fmaf(p0, vb.z, Oa[0][6]); Oa[0][7] = fmaf(p0, vb.w, Oa[0][7]);
            Oa[1][0] = fmaf(p1, va.x, Oa[1][0]); Oa[1][1] = fmaf(p1, va.y, Oa[1][1]);
            Oa[1][2] = fmaf(p1, va.z, Oa[1][2]); Oa[1][3] = fmaf(p1, va.w, Oa[1][3]);
            Oa[1][4] = fmaf(p1, vb.x, Oa[1][4]); Oa[1][5] = fmaf(p1, vb.y, Oa[1][5]);
            Oa[1][6] = fmaf(p1, vb.z, Oa[1][6]); Oa[1][7] = fmaf(p1, vb.w, Oa[1][7]);
        }
    }
    #pragma unroll
    for (int i = 0; i < 2; ++i) {
        int row = q0 + 2 * tr + i;
        if (row < LP) {
            long base = (((long)sp * 8 + b) * LP + row) * 128;
            *(float4*)(Opart + base + (tc << 2))      = make_float4(Oa[i][0], Oa[i][1], Oa[i][2], Oa[i][3]);
            *(float4*)(Opart + base + 64 + (tc << 2)) = make_float4(Oa[i][4], Oa[i][5], Oa[i][6], Oa[i][7]);
            if (tc == 0) {
                mpart[((long)sp * 8 + b) * LP + row] = m_i[i];
                lpart[((long)sp * 8 + b) * LP + row] = l_i[i];
            }
        }
    }
}

// ---------------- megatail: per 16-row tile, all of wo+jp+sigA+tanh-reduce fused ----------------
// grid (63, 8), 256 threads. Att and P never leave LDS. ~66.8 KB LDS -> 2 blocks/CU.
__global__ __launch_bounds__(256) void megatail_k(
    const float* __restrict__ Opart, const float* __restrict__ mp, const float* __restrict__ lp,
    const float* __restrict__ Wvo, const float* __restrict__ bvo,
    const float* __restrict__ jp_w, const float* __restrict__ jp_b,
    const float* __restrict__ Cj, const float* __restrict__ CF,
    float* __restrict__ Asum, float* __restrict__ cpe)
{
    __shared__ __align__(16) float WsA[32][132];   // GEMM W-tiles; rows 0-15 reused as Psh after
    __shared__ __align__(16) float Xt[32][20];
    __shared__ __align__(16) float AttS[16][132];
    __shared__ __align__(16) float Csh[64][132];
    __shared__ float Ash[16][64];
    __shared__ float red[256];
    const int t = threadIdx.x;
    const int p0 = blockIdx.x * 16;
    const int b  = blockIdx.y;
    const float L2E = 1.4426950408889634f;

    // Csh <- Cj tile for this batch
    #pragma unroll
    for (int u = 0; u < 8; ++u) {
        int s = t + u * 256, r = s >> 5, cb = (s & 31) << 2;
        float4 v = *(const float4*)(Cj + ((long)b * NCMP + r) * 128 + cb);
        Csh[r][cb] = v.x; Csh[r][cb+1] = v.y; Csh[r][cb+2] = v.z; Csh[r][cb+3] = v.w;
    }

    // ---- GEMM1: Att = merge2(Opart) @ Wvo + bvo  (16x128, K=128, thread 2r x 4c) ----
    const int r0 = (t >> 5) * 2, c0 = (t & 31) * 4;
    const int xr = t >> 3, xk = (t & 7) << 2;           // staging ids (t<128)
    int prow = p0 + xr; if (prow > LP - 1) prow = LP - 1;
    const long g = (long)b * LP + prow;
    float w0 = 0.f, w1 = 0.f, linv = 0.f;
    if (t < 128) {
        float m0 = mp[g], m1 = mp[g + 8000];
        float l0 = lp[g], l1 = lp[g + 8000];
        float mm = fmaxf(m0, m1);
        w0 = exp2f((m0 - mm) * L2E); w1 = exp2f((m1 - mm) * L2E);
        linv = 1.0f / (w0 * l0 + w1 * l1);
    }
    float4 xv = make_float4(0.f,0.f,0.f,0.f);
    float4 wv[4];
    if (t < 128) {
        float4 a = *(const float4*)(Opart + g * 128 + xk);
        float4 c = *(const float4*)(Opart + 1024000 + g * 128 + xk);
        xv.x = (w0*a.x + w1*c.x) * linv; xv.y = (w0*a.y + w1*c.y) * linv;
        xv.z = (w0*a.z + w1*c.z) * linv; xv.w = (w0*a.w + w1*c.w) * linv;
    }
    #pragma unroll
    for (int u = 0; u < 4; ++u) {
        int s = t + u * 256, r = s >> 5, cb = (s & 31) << 2;
        wv[u] = *(const float4*)(Wvo + (long)r * 128 + cb);
    }
    float acc[2][4] = {};
    for (int k0 = 0; k0 < 128; k0 += 32) {
        if (t < 128) { Xt[xk+0][xr]=xv.x; Xt[xk+1][xr]=xv.y; Xt[xk+2][xr]=xv.z; Xt[xk+3][xr]=xv.w; }
        #pragma unroll
        for (int u = 0; u < 4; ++u) {
            int s = t + u * 256, r = s >> 5, cb = (s & 31) << 2;
            *(float4*)&WsA[r][cb] = wv[u];
        }
        __syncthreads();
        if (k0 + 32 < 128) {
            int kn = k0 + 32;
            if (t < 128) {
                float4 a = *(const float4*)(Opart + g * 128 + kn + xk);
                float4 c = *(const float4*)(Opart + 1024000 + g * 128 + kn + xk);
                xv.x = (w0*a.x + w1*c.x) * linv; xv.y = (w0*a.y + w1*c.y) * linv;
                xv.z = (w0*a.z + w1*c.z) * linv; xv.w = (w0*a.w + w1*c.w) * linv;
            }
            #pragma unroll
            for (int u = 0; u < 4; ++u) {
                int s = t + u * 256, r = s >> 5, cb = (s & 31) << 2;
                wv[u] = *(const float4*)(Wvo + (long)(kn + r) * 128 + cb);
            }
        }
        #pragma unroll
        for (int kk = 0; kk < 32; ++kk) {
            float2 x2 = *(const float2*)&Xt[kk][r0];
            float4 w4 = *(const float4*)&WsA[kk][c0];
            acc[0][0]=fmaf(x2.x,w4.x,acc[0][0]); acc[0][1]=fmaf(x2.x,w4.y,acc[0][1]);
            acc[0][2]=fmaf(x2.x,w4.z,acc[0][2]); acc[0][3]=fmaf(x2.x,w4.w,acc[0][3]);
            acc[1][0]=fmaf(x2.y,w4.x,acc[1][0]); acc[1][1]=fmaf(x2.y,w4.y,acc[1][1]);
            acc[1][2]=fmaf(x2.y,w4.z,acc[1][2]); acc[1][3]=fmaf(x2.y,w4.w,acc[1][3]);
        }
        __syncthreads();
    }
    {   // Att -> AttS (protein_feats, pre-relu, needed by tanh phase)
        float4 bv1 = *(const float4*)(bvo + c0);
        #pragma unroll
        for (int i = 0; i < 2; ++i) {
            float4 o = make_float4(acc[i][0]+bv1.x, acc[i][1]+bv1.y, acc[i][2]+bv1.z, acc[i][3]+bv1.w);
            *(float4*)&AttS[r0 + i][c0] = o;
        }
    }
    // ---- GEMM2: P = relu(Att) @ jp_w + jp_b  (X read from AttS with on-the-fly relu) ----
    float4 wv2[4];
    #pragma unroll
    for (int u = 0; u < 4; ++u) {
        int s = t + u * 256, r = s >> 5, cb = (s & 31) << 2;
        wv2[u] = *(const float4*)(jp_w + (long)r * 128 + cb);
    }
    float ac2[2][4] = {};
    for (int k0 = 0; k0 < 128; k0 += 32) {
        #pragma unroll
        for (int u = 0; u < 4; ++u) {
            int s = t + u * 256, r = s >> 5, cb = (s & 31) << 2;
            *(float4*)&WsA[r][cb] = wv2[u];
        }
        __syncthreads();        // also makes AttS visible on first iteration
        if (k0 + 32 < 128) {
            #pragma unroll
            for (int u = 0; u < 4; ++u) {
                int s = t + u * 256, r = s >> 5, cb = (s & 31) << 2;
                wv2[u] = *(const float4*)(jp_w + (long)(k0 + 32 + r) * 128 + cb);
            }
        }
        #pragma unroll
        for (int kk = 0; kk < 32; ++kk) {
            float x0 = fmaxf(AttS[r0 + 0][k0 + kk], 0.f);   // broadcast reads
            float x1 = fmaxf(AttS[r0 + 1][k0 + kk], 0.f);
            float4 w4 = *(const float4*)&WsA[kk][c0];
            ac2[0][0]=fmaf(x0,w4.x,ac2[0][0]); ac2[0][1]=fmaf(x0,w4.y,ac2[0][1]);
            ac2[0][2]=fmaf(x0,w4.z,ac2[0][2]); ac2[0][3]=fmaf(x0,w4.w,ac2[0][3]);
            ac2[1][0]=fmaf(x1,w4.x,ac2[1][0]); ac2[1][1]=fmaf(x1,w4.y,ac2[1][1]);
            ac2[1][2]=fmaf(x1,w4.z,ac2[1][2]); ac2[1][3]=fmaf(x1,w4.w,ac2[1][3]);
        }
        __syncthreads();
    }
    float (*Psh)[132] = WsA;                      // WsA dead after GEMM2 -> reuse rows 0-15 for P
    {
        float4 b2 = *(const float4*)(jp_b + c0);
        #pragma unroll
        for (int i = 0; i < 2; ++i)
            *(float4*)&Psh[r0 + i][c0] =
                make_float4(ac2[i][0]+b2.x, ac2[i][1]+b2.y, ac2[i][2]+b2.z, ac2[i][3]+b2.w);
    }
    __syncthreads();
    // ---- phase C: A = sigmoid(P Cj^T), Ash + Asum ----
    const int tr = t >> 4, tc = t & 15;
    float sacc[4] = {};
    #pragma unroll 4
    for (int d4 = 0; d4 < 32; ++d4) {
        float4 p4 = *(const float4*)&Psh[tr][d4 << 2];
        #pragma unroll
        for (int j = 0; j < 4; ++j) {
            float4 cv = *(const float4*)&Csh[tc + (j << 4)][d4 << 2];
            sacc[j] += p4.x*cv.x + p4.y*cv.y + p4.z*cv.z + p4.w*cv.w;
        }
    }
    float lsum = 0.f;
    {
        int gi = p0 + tr;
        #pragma unroll
        for (int j = 0; j < 4; ++j) {
            float sg = rcp_fast(1.f + exp2f(-sacc[j] * L2E));
            if (gi < LP) { Ash[tr][tc + (j << 4)] = sg; lsum += sg; }
        }
    }
    red[t] = lsum;
    __syncthreads();
    for (int off = 128; off > 0; off >>= 1) {
        if (t < off) red[t] += red[t + off];
        __syncthreads();
    }
    if (t == 0) atomicAdd(Asum + b, red[0]);
    __syncthreads();
    // Csh <- raw CF
    #pragma unroll
    for (int u = 0; u < 8; ++u) {
        int s = t + u * 256, r = s >> 5, cb = (s & 31) << 2;
        float4 v = *(const float4*)(CF + ((long)b * NCMP + r) * 128 + cb);
        Csh[r][cb] = v.x; Csh[r][cb+1] = v.y; Csh[r][cb+2] = v.z; Csh[r][cb+3] = v.w;
    }
    __syncthreads();
    // ---- phase D: cpe += sum_{i,k} tanh(AttS[i][d] * CF[k][d]) * Ash[i][k] ----
    const float TWO_L2E = 2.8853900817779268f;    // 2*log2(e)
    const int d  = t & 127;
    const int kh = t >> 7;
    const int iiN = (LP - p0 < 16) ? (LP - p0) : 16;
    float accD = 0.f;
    for (int ii = 0; ii < iiN; ++ii) {
        float ptl = AttS[ii][d] * TWO_L2E;
        #pragma unroll
        for (int kk = 0; kk < 32; ++kk) {
            int k = (kh << 5) + kk;
            float e  = exp2f(ptl * Csh[k][d]);           // exp(2x)
            float th = 1.f - 2.f * rcp_fast(e + 1.f);    // tanh(x)
            accD = fmaf(th, Ash[ii][k], accD);
        }
    }
    red[t] = accD;
    __syncthreads();
    if (t < 128) atomicAdd(cpe + (long)b * 128 + t, red[t] + red[t + 128]);
}

// ---------------- classifier head ----------------
__global__ __launch_bounds__(256) void c1h_k(const float* __restrict__ cpe, const float* __restrict__ Asum,
                                             const float* __restrict__ W, const float* __restrict__ bias,
                                             float* __restrict__ h1)
{
    __shared__ float sc[8][128];
    const int t = threadIdx.x;
    #pragma unroll
    for (int u = 0; u < 4; ++u) {
        int idx = t + u * 256;
        sc[idx >> 7][idx & 127] = cpe[idx] * rcp_fast(Asum[idx >> 7]);
    }
    __syncthreads();
    const int b = t >> 5, n = blockIdx.x * 32 + (t & 31);
    float a0 = 0.f, a1 = 0.f, a2 = 0.f, a3 = 0.f;
    #pragma unroll 8
    for (int k = 0; k < 128; k += 4) {
        a0 = fmaf(sc[b][k+0], W[(long)(k+0)*1024 + n], a0);
        a1 = fmaf(sc[b][k+1], W[(long)(k+1)*1024 + n], a1);
        a2 = fmaf(sc[b][k+2], W[(long)(k+2)*1024 + n], a2);
        a3 = fmaf(sc[b][k+3], W[(long)(k+3)*1024 + n], a3);
    }
    h1[b * 1024 + n] = fmaxf((a0 + a1) + (a2 + a3) + bias[n], 0.f);
}

__global__ __launch_bounds__(256) void c2_part_k(const float* __restrict__ in, const float* __restrict__ W,
                                                 float* __restrict__ part)
{
    __shared__ float ins[8][16];
    const int t = threadIdx.x, ks = blockIdx.x, k0 = ks * 16;
    if (t < 128) {
        int b = t >> 4, kk = t & 15;
        ins[b][kk] = in[b * 1024 + k0 + kk];
    }
    __syncthreads();
    const int n = (t & 63) * 4 + (t >> 6) * 256;
    float4 acc[8] = {};
    #pragma unroll
    for (int kk = 0; kk < 16; ++kk) {
        float4 w4 = *(const float4*)(W + (long)(k0 + kk) * 1024 + n);
        #pragma unroll
        for (int b = 0; b < 8; ++b) {
            float s = ins[b][kk];
            acc[b].x = fmaf(s, w4.x, acc[b].x); acc[b].y = fmaf(s, w4.y, acc[b].y);
            acc[b].z = fmaf(s, w4.z, acc[b].z); acc[b].w = fmaf(s, w4.w, acc[b].w);
        }
    }
    #pragma unroll
    for (int b = 0; b < 8; ++b)
        *(float4*)(part + ((long)(ks * 8 + b)) * 1024 + n) = acc[b];
}

__global__ __launch_bounds__(256) void c3m_k(const float* __restrict__ part2, const float* __restrict__ c2_b,
                                             const float* __restrict__ c3_w, const float* __restrict__ c3_b,
                                             const float* __restrict__ c4_w, const float* __restrict__ c4_b,
                                             float* __restrict__ out)
{
    __shared__ float Hs[1024];
    __shared__ float red[256];
    const int t = threadIdx.x, b = blockIdx.x;
    float4 acc4 = make_float4(0.f,0.f,0.f,0.f);
    #pragma unroll 4
    for (int ks = 0; ks < 64; ++ks) {
        float4 p = *(const float4*)(part2 + ((long)(ks * 8 + b)) * 1024 + t * 4);
        acc4.x += p.x; acc4.y += p.y; acc4.z += p.z; acc4.w += p.w;
    }
    {
        float4 bb = *(const float4*)(c2_b + t * 4);
        Hs[t*4+0] = fmaxf(acc4.x + bb.x, 0.f);
        Hs[t*4+1] = fmaxf(acc4.y + bb.y, 0.f);
        Hs[t*4+2] = fmaxf(acc4.z + bb.z, 0.f);
        Hs[t*4+3] = fmaxf(acc4.w + bb.w, 0.f);
    }
    __syncthreads();
    float a0 = 0.f, a1 = 0.f, a2 = 0.f, a3 = 0.f;
    #pragma unroll 8
    for (int k = 0; k < 1024; k += 4) {
        a0 = fmaf(Hs[k+0], c3_w[(long)(k+0)*256 + t], a0);
        a1 = fmaf(Hs[k+1], c3_w[(long)(k+1)*256 + t], a1);
        a2 = fmaf(Hs[k+2], c3_w[(long)(k+2)*256 + t], a2);
        a3 = fmaf(Hs[k+3], c3_w[(long)(k+3)*256 + t], a3);
    }
    float h3v = fmaxf((a0 + a1) + (a2 + a3) + c3_b[t], 0.f);
    red[t] = h3v * c4_w[t];
    __syncthreads();
    for (int off = 128; off > 0; off >>= 1) {
        if (t < off) red[t] += red[t + off];
        __syncthreads();
    }
    if (t == 0) out[b] = red[0] + c4_b[0];
}

extern "C" void kernel_launch(void* const* d_in, const int* in_sizes, int n_in,
                              void* d_out, int out_size, void* d_ws, size_t ws_size,
                              hipStream_t stream)
{
    const float* PE   = (const float*)d_in[0];
    const float* PFX  = (const float*)d_in[1];
    const float* CF   = (const float*)d_in[2];
    const float* emb_w = (const float*)d_in[3];  const float* emb_b = (const float*)d_in[4];
    const float* wq_w  = (const float*)d_in[5];  const float* wq_b  = (const float*)d_in[6];
    const float* wk_w  = (const float*)d_in[7];  const float* wk_b  = (const float*)d_in[8];
    const float* wv_w  = (const float*)d_in[9];  const float* wv_b  = (const float*)d_in[10];
    const float* wo_w  = (const float*)d_in[11]; const float* wo_b  = (const float*)d_in[12];
    const float* jp_w  = (const float*)d_in[13]; const float* jp_b  = (const float*)d_in[14];
    const float* jc_w  = (const float*)d_in[15]; const float* jc_b  = (const float*)d_in[16];
    const float* c1_w  = (const float*)d_in[17]; const float* c1_b  = (const float*)d_in[18];
    const float* c2_w  = (const float*)d_in[19]; const float* c2_b  = (const float*)d_in[20];
    const float* c3_w  = (const float*)d_in[21]; const float* c3_b  = (const float*)d_in[22];
    const float* c4_w  = (const float*)d_in[23]; const float* c4_b  = (const float*)d_in[24];

    float* ws     = (float*)d_ws;
    float* bufQ   = ws;                    // 1,024,000 (Q; later c2-partials alias)
    float* bufK   = bufQ   + 1024000;      // 1,024,000
    float* bufC   = bufK   + 1024000;      //    65,536 (jc output)
    float* Opart  = bufC   + 65536;        // 2,048,000 (2-way flash partials)
    float* mpart  = Opart  + 2048000;      //    16,000
    float* lpart  = mpart  + 16000;        //    16,000
    float* Asum   = lpart  + 16000;        //         8
    float* cpe    = Asum   + 8;            //     1,024
    float* zeros  = cpe    + 1024;         //       128
    float* bprime = zeros  + 128;          //       128 (Q bias)
    float* bufWp  = bprime + 128;          //    40,960 (emb_w @ wq_w)
    float* bufWvo = bufWp  + 40960;        //    16,384 (wv_w @ wo_w)
    float* bufbvo = bufWvo + 16384;        //       128 (wv_b @ wo_w + wo_b)
    float* h1     = bufbvo + 128;          //     8,192
    float* part2  = bufQ;                  // c2 partials alias bufQ (Q dead after flash)
    // total ~4.26M floats = ~17.1 MB

    hipMemsetAsync(Asum, 0, (8 + 1024 + 128) * sizeof(float), stream);   // Asum, cpe, zeros

    pre0_k<<<16, 256, 0, stream>>>(emb_w, emb_b, wq_w, wq_b, wv_w, wv_b, wo_w, wo_b,
                                   zeros, bufWp, bprime, bufWvo, bufbvo);
    qkv_k<<<516, 256, 0, stream>>>(PE, bufWp, bprime, PFX, wk_w, wk_b, CF, jc_w, jc_b,
                                   bufQ, bufK, bufC);
    flash_k<<<dim3(32, 2, 8), 256, 0, stream>>>(bufQ, bufK, PFX, Opart, mpart, lpart);
    megatail_k<<<dim3(63, 8), 256, 0, stream>>>(Opart, mpart, lpart, bufWvo, bufbvo,
                                                jp_w, jp_b, bufC, CF, Asum, cpe);
    c1h_k<<<32, 256, 0, stream>>>(cpe, Asum, c1_w, c1_b, h1);
    c2_part_k<<<64, 256, 0, stream>>>(h1, c2_w, part2);
    c3m_k<<<8, 256, 0, stream>>>(part2, c2_b, c3_w, c3_b, c4_w, c4_b, (float*)d_out);
}